// Round 2
// baseline (937.045 us; speedup 1.0000x reference)
//
#include <hip/hip_runtime.h>

typedef __bf16 bf16x8 __attribute__((ext_vector_type(8)));
typedef float  f32x4  __attribute__((ext_vector_type(4)));
typedef float  f32x16 __attribute__((ext_vector_type(16)));

__device__ __forceinline__ unsigned short f2b(float f) {
    union { float f; unsigned int v; } c; c.f = f;
    unsigned int u = c.v;
    unsigned int r = u + 0x7FFFu + ((u >> 16) & 1u);   // RNE
    return (unsigned short)(r >> 16);
}
__device__ __forceinline__ f32x4 mfma16(bf16x8 a, bf16x8 b, f32x4 c) {
    return __builtin_amdgcn_mfma_f32_16x16x32_bf16(a, b, c, 0, 0, 0);
}
__device__ __forceinline__ f32x16 mfma32(bf16x8 a, bf16x8 b, f32x16 c) {
    return __builtin_amdgcn_mfma_f32_32x32x16_bf16(a, b, c, 0, 0, 0);
}
// pack two f32 -> 2xbf16 in one u32 (lo = a, hi = b), RNE
__device__ __forceinline__ unsigned cvtpk(float a, float b) {
    unsigned r;
    asm("v_cvt_pk_bf16_f32 %0, %1, %2" : "=v"(r) : "v"(a), "v"(b));
    return r;
}

// ---------------- constants ----------------
#define BB 8
#define SS 2048
#define DD 256
#define HH 4
#define FF 512
#define MM (BB * SS)   // 16384
// log2(e) folded into Q scale so softmax uses exp2 directly
#define QSCALE (0.0625f * 1.44269504088896340736f)

// ---------------- transpose f32 -> bf16 with scale ----------------
__global__ __launch_bounds__(256) void transpose_f32_kernel(
    const float* __restrict__ in, unsigned short* __restrict__ out,
    int inS, int outS, long long inZa, long long inZb, int zmod, long long outZ,
    float scale)
{
    __shared__ unsigned short T[64][72];
    const int z = blockIdx.z;
    in  += (long long)(z / zmod) * inZa + (long long)(z % zmod) * inZb;
    out += (long long)z * outZ;
    const int r0 = blockIdx.x * 64, c0 = blockIdx.y * 64;
    const int tid = threadIdx.x;
    const int row = tid >> 3;           // 0..31
    const int col = (tid & 7) * 8;      // 0..56
#pragma unroll
    for (int c = 0; c < 2; ++c) {
        int rr = c * 32 + row;
        const float4 a = *reinterpret_cast<const float4*>(&in[(long long)(r0 + rr) * inS + c0 + col]);
        const float4 b = *reinterpret_cast<const float4*>(&in[(long long)(r0 + rr) * inS + c0 + col + 4]);
        alignas(16) unsigned short t[8] = {
            f2b(a.x * scale), f2b(a.y * scale), f2b(a.z * scale), f2b(a.w * scale),
            f2b(b.x * scale), f2b(b.y * scale), f2b(b.z * scale), f2b(b.w * scale) };
        *reinterpret_cast<uint4*>(&T[rr][col]) = *reinterpret_cast<const uint4*>(t);
    }
    __syncthreads();
#pragma unroll
    for (int c = 0; c < 2; ++c) {
        int orow = c * 32 + row;
        alignas(16) unsigned short tmp[8];
#pragma unroll
        for (int j = 0; j < 8; ++j) tmp[j] = T[col + j][orow];
        *reinterpret_cast<uint4*>(&out[(long long)(c0 + orow) * outS + r0 + col]) =
            *reinterpret_cast<const uint4*>(tmp);
    }
}

// ---------------- bias concat: qkb[2048] = {bq*QSCALE, bk}, vb[1024] = bv ----------------
__global__ __launch_bounds__(256) void bias_concat_kernel(
    const float* __restrict__ bq, const float* __restrict__ bk,
    const float* __restrict__ bv, float* __restrict__ qkb, float* __restrict__ vb)
{
    const int i = blockIdx.x * 256 + threadIdx.x;
    if (i < 1024)       qkb[i] = bq[i] * QSCALE;
    else if (i < 2048)  qkb[i] = bk[i - 1024];
    else                vb[i - 2048] = bv[i - 2048];
}

// ---------------- LayerNorm: one wave per 256-elem row, f32 in -> bf16 out ----------------
__global__ __launch_bounds__(256) void ln_kernel(
    const float* __restrict__ in, const float* __restrict__ g,
    const float* __restrict__ bta, unsigned short* __restrict__ out)
{
    const int tid  = threadIdx.x;
    const int wave = tid >> 6, lane = tid & 63;
    const int row  = blockIdx.x * 4 + wave;
    const float4 v = reinterpret_cast<const float4*>(in)[(long long)row * 64 + lane];
    float x[4] = { v.x, v.y, v.z, v.w };
    float s = x[0] + x[1] + x[2] + x[3];
    float q = x[0]*x[0] + x[1]*x[1] + x[2]*x[2] + x[3]*x[3];
#pragma unroll
    for (int off = 1; off < 64; off <<= 1) {
        s += __shfl_xor(s, off);
        q += __shfl_xor(q, off);
    }
    const float mean = s * (1.0f / 256.0f);
    const float var  = q * (1.0f / 256.0f) - mean * mean;
    const float rs   = rsqrtf(var + 1e-5f);
    const float4 gv = reinterpret_cast<const float4*>(g)[lane];
    const float4 bv = reinterpret_cast<const float4*>(bta)[lane];
    unsigned short y[4];
    y[0] = f2b((x[0] - mean) * rs * gv.x + bv.x);
    y[1] = f2b((x[1] - mean) * rs * gv.y + bv.y);
    y[2] = f2b((x[2] - mean) * rs * gv.z + bv.z);
    y[3] = f2b((x[3] - mean) * rs * gv.w + bv.w);
    uint2 o;
    o.x = (unsigned int)y[0] | ((unsigned int)y[1] << 16);
    o.y = (unsigned int)y[2] | ((unsigned int)y[3] << 16);
    reinterpret_cast<uint2*>(out)[(long long)row * 64 + lane] = o;
}

// ---------------- GEMM: C[MxN] = A[MxK] @ B  (B given as BT[N x K], bf16) ----------------
template <bool RELU, int RES, bool OUTBF, int NS, bool VT>
__global__ __launch_bounds__(256) void gemm_kernel(
    const unsigned short* __restrict__ A, const unsigned short* __restrict__ BT,
    const float* __restrict__ bias, const float* __restrict__ res,
    void* __restrict__ out, int M, int N, int K)
{
    __shared__ unsigned short As[128 * 40];
    __shared__ unsigned short Bs[(NS == 4 ? 128 : 64) * 40];
    const int tid  = threadIdx.x;
    const int wave = tid >> 6, lane = tid & 63;
    const int quad = lane >> 4, l16 = lane & 15;
    const int wm = wave >> 1, wn = wave & 1;
    const int WN = NS * 16;                        // wave n-width
    const int m0 = blockIdx.x * 128, n0 = blockIdx.y * (2 * WN);

    f32x4 acc[4][NS];
#pragma unroll
    for (int i = 0; i < 4; ++i)
#pragma unroll
        for (int j = 0; j < NS; ++j) acc[i][j] = (f32x4){0.f, 0.f, 0.f, 0.f};

    const int srow = tid >> 2;          // 0..63
    const int scol = (tid & 3) * 8;     // 0,8,16,24

    for (int k0 = 0; k0 < K; k0 += 32) {
        __syncthreads();
#pragma unroll
        for (int c = 0; c < 2; ++c) {
            const int r = c * 64 + srow;
            *reinterpret_cast<uint4*>(&As[r * 40 + scol]) =
                *reinterpret_cast<const uint4*>(&A[(long long)(m0 + r) * K + k0 + scol]);
        }
        {
            *reinterpret_cast<uint4*>(&Bs[srow * 40 + scol]) =
                *reinterpret_cast<const uint4*>(&BT[(long long)(n0 + srow) * K + k0 + scol]);
            if (NS == 4) {
                const int r = 64 + srow;
                *reinterpret_cast<uint4*>(&Bs[r * 40 + scol]) =
                    *reinterpret_cast<const uint4*>(&BT[(long long)(n0 + r) * K + k0 + scol]);
            }
        }
        __syncthreads();
        bf16x8 af[4], bf[NS];
#pragma unroll
        for (int ms = 0; ms < 4; ++ms)
            af[ms] = *reinterpret_cast<const bf16x8*>(&As[(wm * 64 + ms * 16 + l16) * 40 + quad * 8]);
#pragma unroll
        for (int ns = 0; ns < NS; ++ns)
            bf[ns] = *reinterpret_cast<const bf16x8*>(&Bs[(wn * WN + ns * 16 + l16) * 40 + quad * 8]);
#pragma unroll
        for (int ms = 0; ms < 4; ++ms)
#pragma unroll
            for (int ns = 0; ns < NS; ++ns)
                acc[ms][ns] = mfma16(af[ms], bf[ns], acc[ms][ns]);
    }

    // epilogue
#pragma unroll
    for (int ms = 0; ms < 4; ++ms) {
#pragma unroll
        for (int ns = 0; ns < NS; ++ns) {
            const int cg = n0 + wn * WN + ns * 16 + l16;
            const float bvc = VT ? 0.f : bias[cg];
#pragma unroll
            for (int r = 0; r < 4; ++r) {
                const int rg = m0 + wm * 64 + ms * 16 + quad * 4 + r;
                float v = acc[ms][ns][r] + (VT ? bias[rg] : bvc);
                if (RELU)   v = fmaxf(v, 0.0f);
                if (RES == 1)
                    v += res[(long long)rg * N + cg];
                if (VT) {
                    const long long oaddr =
                        (long long)((cg >> 11) * 4 + (rg >> 8)) * 524288 +
                        (long long)(rg & 255) * 2048 + (cg & 2047);
                    reinterpret_cast<unsigned short*>(out)[oaddr] = f2b(v);
                } else if (OUTBF) {
                    reinterpret_cast<unsigned short*>(out)[(long long)rg * N + cg] = f2b(v);
                } else {
                    reinterpret_cast<float*>(out)[(long long)rg * N + cg] = v;
                }
            }
        }
    }
}

// ---------------- Flash attention: one-tile-behind softmax pipeline ----------------
// Iteration t: write Ks(t+1) | barrier | write Vs(t+1) | QK(t+1) [MFMA] ∥ exp/pack(t) [VALU]
//              | load tile t+2 -> regs | PV(t) [MFMA].
// Buffer discipline (tile T lives in buf T&1, single barrier/iter):
//   Ks(t+1) write pre-barrier: prior reader QK(t-1) finished before iter(t-1)'s barrier.
//   Vs(t+1) write post-barrier: prior reader PV(t-1) fenced by THIS iteration's barrier.
//   PV(t) reads Vs[t&1] vs next iter's Vs(t+2) write into same buf: fenced by iter(t+1) barrier.
// LDS: 2*(32*264 + 256*40)*2B = 74752 B -> 2 blocks/CU.
__global__ __launch_bounds__(256, 2) void attn_kernel(
    const unsigned short* __restrict__ QK, const unsigned short* __restrict__ Vt,
    unsigned short* __restrict__ Cat)
{
    __shared__ __align__(16) unsigned short Ks[2][32 * 264];   // [t][d], stride 264
    __shared__ __align__(16) unsigned short Vs[2][256 * 40];   // [e][t], stride 40
    const int tid  = threadIdx.x;
    const int wave = tid >> 6, lane = tid & 63;
    const int l32 = lane & 31, half = lane >> 5;
    const int by = blockIdx.x;              // b*4 + h
    const int h = by & 3, b = by >> 2;
    const int q0 = blockIdx.y * 128;
    const unsigned short* Qb = QK + (long long)b * SS * 2048 + h * 256;
    const unsigned short* Kb = Qb + 1024;
    const unsigned short* vbase = Vt + (long long)by * DD * SS;

    // Q fragments, 32 rows/wave: lane holds Q[q0+w*32+l32][kb*16 + half*8 + j]
    bf16x8 qf[16];
    {
        const unsigned short* qrow = Qb + (long long)(q0 + wave * 32 + l32) * 2048 + half * 8;
#pragma unroll
        for (int kb = 0; kb < 16; ++kb)
            qf[kb] = *reinterpret_cast<const bf16x8*>(qrow + kb * 16);
    }

    f32x16 o[8];
#pragma unroll
    for (int i = 0; i < 8; ++i)
#pragma unroll
        for (int r = 0; r < 16; ++r) o[i][r] = 0.f;
    float lsum = 0.f;   // per-lane partial row-sum for q = l32 (this half's t-subset)

    const int krow = tid >> 3;          // 0..31
    const int kcol = (tid & 7) * 8;     // 0..56 (shorts)
    const int ve   = tid >> 2;          // 0..63 (base V row)
    const int vtf  = (tid & 3) * 8;     // 0..24 (t offset, shorts)

    uint4 kreg[4], vreg[4];
    // prologue: stage tile 0 into buffer 0
#pragma unroll
    for (int c = 0; c < 4; ++c)
        kreg[c] = *reinterpret_cast<const uint4*>(&Kb[(long long)krow * 2048 + kcol + c * 64]);
#pragma unroll
    for (int c = 0; c < 4; ++c)
        vreg[c] = *reinterpret_cast<const uint4*>(&vbase[(long long)(ve + c * 64) * SS + vtf]);
#pragma unroll
    for (int c = 0; c < 4; ++c)
        *reinterpret_cast<uint4*>(&Ks[0][krow * 264 + kcol + c * 64]) = kreg[c];
#pragma unroll
    for (int c = 0; c < 4; ++c)
        *reinterpret_cast<uint4*>(&Vs[0][(ve + c * 64) * 40 + vtf]) = vreg[c];
    __syncthreads();

    f32x16 scA, scB;
    // QK(0) -> scA
    {
#pragma unroll
        for (int r = 0; r < 16; ++r) scA[r] = 0.f;
        __builtin_amdgcn_s_setprio(1);
#pragma unroll
        for (int kb = 0; kb < 16; ++kb) {
            bf16x8 kf = *reinterpret_cast<const bf16x8*>(&Ks[0][l32 * 264 + kb * 16 + half * 8]);
            scA = mfma32(kf, qf[kb], scA);
        }
        __builtin_amdgcn_s_setprio(0);
        // load tile 1 -> regs
#pragma unroll
        for (int c = 0; c < 4; ++c)
            kreg[c] = *reinterpret_cast<const uint4*>(&Kb[(long long)(32 + krow) * 2048 + kcol + c * 64]);
#pragma unroll
        for (int c = 0; c < 4; ++c)
            vreg[c] = *reinterpret_cast<const uint4*>(&vbase[(long long)(ve + c * 64) * SS + 32 + vtf]);
    }

#define ATTN_BODY(SCC, SCN, T, CUR, NXT)                                                        \
    {                                                                                           \
        _Pragma("unroll")                                                                       \
        for (int c = 0; c < 4; ++c)                                                             \
            *reinterpret_cast<uint4*>(&Ks[NXT][krow * 264 + kcol + c * 64]) = kreg[c];          \
        __syncthreads();                                                                        \
        _Pragma("unroll")                                                                       \
        for (int c = 0; c < 4; ++c)                                                             \
            *reinterpret_cast<uint4*>(&Vs[NXT][(ve + c * 64) * 40 + vtf]) = vreg[c];            \
        _Pragma("unroll")                                                                       \
        for (int r = 0; r < 16; ++r) SCN[r] = 0.f;                                              \
        __builtin_amdgcn_s_setprio(1);                                                          \
        _Pragma("unroll")                                                                       \
        for (int kb = 0; kb < 16; ++kb) {                                                       \
            bf16x8 kf = *reinterpret_cast<const bf16x8*>(&Ks[NXT][l32 * 264 + kb * 16 + half * 8]); \
            SCN = mfma32(kf, qf[kb], SCN);                                                      \
        }                                                                                       \
        __builtin_amdgcn_s_setprio(0);                                                          \
        float p[16];                                                                            \
        _Pragma("unroll")                                                                       \
        for (int r = 0; r < 16; ++r) { p[r] = exp2f(SCC[r]); lsum += p[r]; }                    \
        unsigned pk[8];                                                                         \
        _Pragma("unroll")                                                                       \
        for (int i = 0; i < 8; ++i) pk[i] = cvtpk(p[2 * i], p[2 * i + 1]);                      \
        union { bf16x8 v; unsigned u[4]; } A0, A1;                                              \
        { auto rr = __builtin_amdgcn_permlane32_swap(pk[0], pk[2], false, false); A0.u[0] = rr[0]; A0.u[2] = rr[1]; } \
        { auto rr = __builtin_amdgcn_permlane32_swap(pk[1], pk[3], false, false); A0.u[1] = rr[0]; A0.u[3] = rr[1]; } \
        { auto rr = __builtin_amdgcn_permlane32_swap(pk[4], pk[6], false, false); A1.u[0] = rr[0]; A1.u[2] = rr[1]; } \
        { auto rr = __builtin_amdgcn_permlane32_swap(pk[5], pk[7], false, false); A1.u[1] = rr[0]; A1.u[3] = rr[1]; } \
        {                                                                                       \
            const int t2 = ((T) + 2 <= 63 ? (T) + 2 : 63) * 32;                                 \
            _Pragma("unroll")                                                                   \
            for (int c = 0; c < 4; ++c)                                                         \
                kreg[c] = *reinterpret_cast<const uint4*>(&Kb[(long long)(t2 + krow) * 2048 + kcol + c * 64]); \
            _Pragma("unroll")                                                                   \
            for (int c = 0; c < 4; ++c)                                                         \
                vreg[c] = *reinterpret_cast<const uint4*>(&vbase[(long long)(ve + c * 64) * SS + t2 + vtf]); \
        }                                                                                       \
        __builtin_amdgcn_s_setprio(1);                                                          \
        _Pragma("unroll")                                                                       \
        for (int et = 0; et < 8; ++et) {                                                        \
            bf16x8 vf0 = *reinterpret_cast<const bf16x8*>(&Vs[CUR][(et * 32 + l32) * 40 + half * 8]);      \
            bf16x8 vf1 = *reinterpret_cast<const bf16x8*>(&Vs[CUR][(et * 32 + l32) * 40 + 16 + half * 8]); \
            o[et] = mfma32(A0.v, vf0, o[et]);                                                   \
            o[et] = mfma32(A1.v, vf1, o[et]);                                                   \
        }                                                                                       \
        __builtin_amdgcn_s_setprio(0);                                                          \
    }

    for (int t = 0; t < 62; t += 2) {
        ATTN_BODY(scA, scB, t, 0, 1);
        ATTN_BODY(scB, scA, t + 1, 1, 0);
    }
    ATTN_BODY(scA, scB, 62, 0, 1);
#undef ATTN_BODY

    // tail: tile 63 (sc in scB, V in Vs[1]); barrier needed so all waves' Vs(63) writes landed
    __syncthreads();
    {
        float p[16];
#pragma unroll
        for (int r = 0; r < 16; ++r) { p[r] = exp2f(scB[r]); lsum += p[r]; }
        unsigned pk[8];
#pragma unroll
        for (int i = 0; i < 8; ++i) pk[i] = cvtpk(p[2 * i], p[2 * i + 1]);
        union { bf16x8 v; unsigned u[4]; } A0, A1;
        { auto rr = __builtin_amdgcn_permlane32_swap(pk[0], pk[2], false, false); A0.u[0] = rr[0]; A0.u[2] = rr[1]; }
        { auto rr = __builtin_amdgcn_permlane32_swap(pk[1], pk[3], false, false); A0.u[1] = rr[0]; A0.u[3] = rr[1]; }
        { auto rr = __builtin_amdgcn_permlane32_swap(pk[4], pk[6], false, false); A1.u[0] = rr[0]; A1.u[2] = rr[1]; }
        { auto rr = __builtin_amdgcn_permlane32_swap(pk[5], pk[7], false, false); A1.u[1] = rr[0]; A1.u[3] = rr[1]; }
        __builtin_amdgcn_s_setprio(1);
#pragma unroll
        for (int et = 0; et < 8; ++et) {
            bf16x8 vf0 = *reinterpret_cast<const bf16x8*>(&Vs[1][(et * 32 + l32) * 40 + half * 8]);
            bf16x8 vf1 = *reinterpret_cast<const bf16x8*>(&Vs[1][(et * 32 + l32) * 40 + 16 + half * 8]);
            o[et] = mfma32(A0.v, vf0, o[et]);
            o[et] = mfma32(A1.v, vf1, o[et]);
        }
        __builtin_amdgcn_s_setprio(0);
    }

    // epilogue: full row-sum for q=l32 lives split across the two halves
    lsum += __shfl_xor(lsum, 32);
    const float inv = 1.0f / lsum;
    float invr[16];
#pragma unroll
    for (int r = 0; r < 16; ++r)
        invr[r] = __shfl(inv, (r & 3) + 8 * (r >> 2) + 4 * half);

    const int rowb = b * SS + q0 + wave * 32;
#pragma unroll
    for (int et = 0; et < 8; ++et) {
        const int cg = h * 256 + et * 32 + l32;
#pragma unroll
        for (int r = 0; r < 16; ++r) {
            const int row = (r & 3) + 8 * (r >> 2) + 4 * half;
            Cat[(long long)(rowb + row) * (HH * DD) + cg] = f2b(o[et][r] * invr[r]);
        }
    }
}

// ---------------- launch ----------------
extern "C" void kernel_launch(void* const* d_in, const int* in_sizes, int n_in,
                              void* d_out, int out_size, void* d_ws, size_t ws_size,
                              hipStream_t stream)
{
    const float* x   = (const float*)d_in[0];
    const float* Wq  = (const float*)d_in[1];
    const float* bq  = (const float*)d_in[2];
    const float* Wk  = (const float*)d_in[3];
    const float* bk  = (const float*)d_in[4];
    const float* Wv  = (const float*)d_in[5];
    const float* bv  = (const float*)d_in[6];
    const float* Wo  = (const float*)d_in[7];
    const float* bo  = (const float*)d_in[8];
    const float* g1  = (const float*)d_in[9];
    const float* be1 = (const float*)d_in[10];
    const float* g2  = (const float*)d_in[11];
    const float* be2 = (const float*)d_in[12];
    const float* W1  = (const float*)d_in[13];
    const float* bf1 = (const float*)d_in[14];
    const float* W2  = (const float*)d_in[15];
    const float* bf2 = (const float*)d_in[16];
    float* out = (float*)d_out;

    // ---- workspace layout ----
    char* ws = (char*)d_ws;
    unsigned short* xn1  = (unsigned short*)(ws + 0);           // [16384][256] bf16
    unsigned short* qk   = (unsigned short*)(ws + 8388608);     // [16384][2048] bf16 (Q|K by head)
    unsigned short* cat  = (unsigned short*)(ws + 75497472);    // [16384][1024] bf16
    unsigned short* vt   = (unsigned short*)(ws + 109051904);   // [32][256][2048] bf16
    unsigned short* wqkT = (unsigned short*)(ws + 142606336);   // [2048][256] bf16
    unsigned short* wvT  = (unsigned short*)(ws + 143654912);   // [1024][256] bf16
    unsigned short* woT  = (unsigned short*)(ws + 144179200);   // [256][1024] bf16
    unsigned short* w1T  = (unsigned short*)(ws + 144703488);   // [512][256] bf16
    unsigned short* w2T  = (unsigned short*)(ws + 144965632);   // [256][512] bf16
    float*          qkb  = (float*)(ws + 145227776);            // [2048] f32
    float*          vb   = (float*)(ws + 145235968);            // [1024] f32
    // aliases over dead regions:
    float*          xmid = (float*)(ws + 8388608);              // (qk dead after attn)
    unsigned short* xn2  = (unsigned short*)(ws + 25165824);
    unsigned short* mid  = (unsigned short*)(ws + 33554432);

    // weight transposes (Q scale: 1/16 * log2(e) folded for exp2 softmax)
    transpose_f32_kernel<<<dim3(4, 4, 4),  256, 0, stream>>>(Wq, wqkT,          256,  256, 0, 65536, 4, 65536, QSCALE);
    transpose_f32_kernel<<<dim3(4, 4, 4),  256, 0, stream>>>(Wk, wqkT + 262144, 256,  256, 0, 65536, 4, 65536, 1.0f);
    transpose_f32_kernel<<<dim3(4, 4, 4),  256, 0, stream>>>(Wv, wvT,           256,  256, 0, 65536, 4, 65536, 1.0f);
    transpose_f32_kernel<<<dim3(16, 4, 1), 256, 0, stream>>>(Wo, woT,           256, 1024, 0, 0, 4, 0, 1.0f);
    transpose_f32_kernel<<<dim3(4, 8, 1),  256, 0, stream>>>(W1, w1T,           512,  256, 0, 0, 4, 0, 1.0f);
    transpose_f32_kernel<<<dim3(8, 4, 1),  256, 0, stream>>>(W2, w2T,           256,  512, 0, 0, 4, 0, 1.0f);
    bias_concat_kernel<<<dim3(12), 256, 0, stream>>>(bq, bk, bv, qkb, vb);

    // LN1
    ln_kernel<<<dim3(4096), 256, 0, stream>>>(x, g1, be1, xn1);

    // fused Q|K projection (2048 blocks)
    gemm_kernel<false, 0, true, 4, false><<<dim3(128, 16), 256, 0, stream>>>(
        xn1, wqkT, qkb, nullptr, qk, MM, 2048, 256);
    // V^T projection straight into vt layout (1024 blocks)
    gemm_kernel<false, 0, true, 4, true><<<dim3(8, 128), 256, 0, stream>>>(
        wvT, xn1, vb, nullptr, vt, 1024, MM, 256);

    // flash attention (32x32 MFMA, 128 q-rows/block, 512 blocks = 2/CU)
    attn_kernel<<<dim3(32, 16), 256, 0, stream>>>(qk, vt, cat);

    // Wo projection + residual(x) -> xmid (f32); 128x64 tiles -> 512 blocks
    gemm_kernel<false, 1, false, 2, false><<<dim3(128, 4), 256, 0, stream>>>(
        cat, woT, bo, x, xmid, MM, 256, 1024);

    // LN2
    ln_kernel<<<dim3(4096), 256, 0, stream>>>(xmid, g2, be2, xn2);

    // FFN1 + ReLU; 128x64 tiles -> 1024 blocks
    gemm_kernel<true, 0, true, 2, false><<<dim3(128, 8), 256, 0, stream>>>(
        xn2, w1T, bf1, nullptr, mid, MM, 512, 256);

    // FFN2 + residual(xmid) -> d_out (f32); 128x64 tiles -> 512 blocks
    gemm_kernel<false, 1, false, 2, false><<<dim3(128, 4), 256, 0, stream>>>(
        mid, w2T, bf2, xmid, out, MM, 256, 512);

    (void)in_sizes; (void)n_in; (void)out_size; (void)ws_size;
}

// Round 4
// 504.931 us; speedup vs baseline: 1.8558x; 1.8558x over previous
//
#include <hip/hip_runtime.h>

typedef __bf16 bf16x8 __attribute__((ext_vector_type(8)));
typedef float  f32x4  __attribute__((ext_vector_type(4)));
typedef float  f32x16 __attribute__((ext_vector_type(16)));

__device__ __forceinline__ unsigned short f2b(float f) {
    union { float f; unsigned int v; } c; c.f = f;
    unsigned int u = c.v;
    unsigned int r = u + 0x7FFFu + ((u >> 16) & 1u);   // RNE
    return (unsigned short)(r >> 16);
}
__device__ __forceinline__ f32x4 mfma16(bf16x8 a, bf16x8 b, f32x4 c) {
    return __builtin_amdgcn_mfma_f32_16x16x32_bf16(a, b, c, 0, 0, 0);
}
__device__ __forceinline__ f32x16 mfma32(bf16x8 a, bf16x8 b, f32x16 c) {
    return __builtin_amdgcn_mfma_f32_32x32x16_bf16(a, b, c, 0, 0, 0);
}
// pack two f32 -> 2xbf16 in one u32 (lo = a, hi = b), RNE
__device__ __forceinline__ unsigned cvtpk(float a, float b) {
    unsigned r;
    asm("v_cvt_pk_bf16_f32 %0, %1, %2" : "=v"(r) : "v"(a), "v"(b));
    return r;
}

// ---------------- constants ----------------
#define BB 8
#define SS 2048
#define DD 256
#define HH 4
#define FF 512
#define MM (BB * SS)   // 16384
// log2(e) folded into Q scale so softmax uses exp2 directly
#define QSCALE (0.0625f * 1.44269504088896340736f)

// ---------------- transpose f32 -> bf16 with scale ----------------
__global__ __launch_bounds__(256) void transpose_f32_kernel(
    const float* __restrict__ in, unsigned short* __restrict__ out,
    int inS, int outS, long long inZa, long long inZb, int zmod, long long outZ,
    float scale)
{
    __shared__ unsigned short T[64][72];
    const int z = blockIdx.z;
    in  += (long long)(z / zmod) * inZa + (long long)(z % zmod) * inZb;
    out += (long long)z * outZ;
    const int r0 = blockIdx.x * 64, c0 = blockIdx.y * 64;
    const int tid = threadIdx.x;
    const int row = tid >> 3;           // 0..31
    const int col = (tid & 7) * 8;      // 0..56
#pragma unroll
    for (int c = 0; c < 2; ++c) {
        int rr = c * 32 + row;
        const float4 a = *reinterpret_cast<const float4*>(&in[(long long)(r0 + rr) * inS + c0 + col]);
        const float4 b = *reinterpret_cast<const float4*>(&in[(long long)(r0 + rr) * inS + c0 + col + 4]);
        alignas(16) unsigned short t[8] = {
            f2b(a.x * scale), f2b(a.y * scale), f2b(a.z * scale), f2b(a.w * scale),
            f2b(b.x * scale), f2b(b.y * scale), f2b(b.z * scale), f2b(b.w * scale) };
        *reinterpret_cast<uint4*>(&T[rr][col]) = *reinterpret_cast<const uint4*>(t);
    }
    __syncthreads();
#pragma unroll
    for (int c = 0; c < 2; ++c) {
        int orow = c * 32 + row;
        alignas(16) unsigned short tmp[8];
#pragma unroll
        for (int j = 0; j < 8; ++j) tmp[j] = T[col + j][orow];
        *reinterpret_cast<uint4*>(&out[(long long)(c0 + orow) * outS + r0 + col]) =
            *reinterpret_cast<const uint4*>(tmp);
    }
}

// ---------------- bias concat: qkb[2048] = {bq*QSCALE, bk}, vb[1024] = bv ----------------
__global__ __launch_bounds__(256) void bias_concat_kernel(
    const float* __restrict__ bq, const float* __restrict__ bk,
    const float* __restrict__ bv, float* __restrict__ qkb, float* __restrict__ vb)
{
    const int i = blockIdx.x * 256 + threadIdx.x;
    if (i < 1024)       qkb[i] = bq[i] * QSCALE;
    else if (i < 2048)  qkb[i] = bk[i - 1024];
    else                vb[i - 2048] = bv[i - 2048];
}

// ---------------- LayerNorm: one wave per 256-elem row, f32 in -> bf16 out ----------------
__global__ __launch_bounds__(256) void ln_kernel(
    const float* __restrict__ in, const float* __restrict__ g,
    const float* __restrict__ bta, unsigned short* __restrict__ out)
{
    const int tid  = threadIdx.x;
    const int wave = tid >> 6, lane = tid & 63;
    const int row  = blockIdx.x * 4 + wave;
    const float4 v = reinterpret_cast<const float4*>(in)[(long long)row * 64 + lane];
    float x[4] = { v.x, v.y, v.z, v.w };
    float s = x[0] + x[1] + x[2] + x[3];
    float q = x[0]*x[0] + x[1]*x[1] + x[2]*x[2] + x[3]*x[3];
#pragma unroll
    for (int off = 1; off < 64; off <<= 1) {
        s += __shfl_xor(s, off);
        q += __shfl_xor(q, off);
    }
    const float mean = s * (1.0f / 256.0f);
    const float var  = q * (1.0f / 256.0f) - mean * mean;
    const float rs   = rsqrtf(var + 1e-5f);
    const float4 gv = reinterpret_cast<const float4*>(g)[lane];
    const float4 bv = reinterpret_cast<const float4*>(bta)[lane];
    unsigned short y[4];
    y[0] = f2b((x[0] - mean) * rs * gv.x + bv.x);
    y[1] = f2b((x[1] - mean) * rs * gv.y + bv.y);
    y[2] = f2b((x[2] - mean) * rs * gv.z + bv.z);
    y[3] = f2b((x[3] - mean) * rs * gv.w + bv.w);
    uint2 o;
    o.x = (unsigned int)y[0] | ((unsigned int)y[1] << 16);
    o.y = (unsigned int)y[2] | ((unsigned int)y[3] << 16);
    reinterpret_cast<uint2*>(out)[(long long)row * 64 + lane] = o;
}

// ---------------- GEMM: C[MxN] = A[MxK] @ B  (B given as BT[N x K], bf16) ----------------
template <bool RELU, int RES, bool OUTBF, int NS, bool VT>
__global__ __launch_bounds__(256) void gemm_kernel(
    const unsigned short* __restrict__ A, const unsigned short* __restrict__ BT,
    const float* __restrict__ bias, const float* __restrict__ res,
    void* __restrict__ out, int M, int N, int K)
{
    __shared__ unsigned short As[128 * 40];
    __shared__ unsigned short Bs[(NS == 4 ? 128 : 64) * 40];
    const int tid  = threadIdx.x;
    const int wave = tid >> 6, lane = tid & 63;
    const int quad = lane >> 4, l16 = lane & 15;
    const int wm = wave >> 1, wn = wave & 1;
    const int WN = NS * 16;                        // wave n-width
    const int m0 = blockIdx.x * 128, n0 = blockIdx.y * (2 * WN);

    f32x4 acc[4][NS];
#pragma unroll
    for (int i = 0; i < 4; ++i)
#pragma unroll
        for (int j = 0; j < NS; ++j) acc[i][j] = (f32x4){0.f, 0.f, 0.f, 0.f};

    const int srow = tid >> 2;          // 0..63
    const int scol = (tid & 3) * 8;     // 0,8,16,24

    for (int k0 = 0; k0 < K; k0 += 32) {
        __syncthreads();
#pragma unroll
        for (int c = 0; c < 2; ++c) {
            const int r = c * 64 + srow;
            *reinterpret_cast<uint4*>(&As[r * 40 + scol]) =
                *reinterpret_cast<const uint4*>(&A[(long long)(m0 + r) * K + k0 + scol]);
        }
        {
            *reinterpret_cast<uint4*>(&Bs[srow * 40 + scol]) =
                *reinterpret_cast<const uint4*>(&BT[(long long)(n0 + srow) * K + k0 + scol]);
            if (NS == 4) {
                const int r = 64 + srow;
                *reinterpret_cast<uint4*>(&Bs[r * 40 + scol]) =
                    *reinterpret_cast<const uint4*>(&BT[(long long)(n0 + r) * K + k0 + scol]);
            }
        }
        __syncthreads();
        bf16x8 af[4], bf[NS];
#pragma unroll
        for (int ms = 0; ms < 4; ++ms)
            af[ms] = *reinterpret_cast<const bf16x8*>(&As[(wm * 64 + ms * 16 + l16) * 40 + quad * 8]);
#pragma unroll
        for (int ns = 0; ns < NS; ++ns)
            bf[ns] = *reinterpret_cast<const bf16x8*>(&Bs[(wn * WN + ns * 16 + l16) * 40 + quad * 8]);
#pragma unroll
        for (int ms = 0; ms < 4; ++ms)
#pragma unroll
            for (int ns = 0; ns < NS; ++ns)
                acc[ms][ns] = mfma16(af[ms], bf[ns], acc[ms][ns]);
    }

    // epilogue
#pragma unroll
    for (int ms = 0; ms < 4; ++ms) {
#pragma unroll
        for (int ns = 0; ns < NS; ++ns) {
            const int cg = n0 + wn * WN + ns * 16 + l16;
            const float bvc = VT ? 0.f : bias[cg];
#pragma unroll
            for (int r = 0; r < 4; ++r) {
                const int rg = m0 + wm * 64 + ms * 16 + quad * 4 + r;
                float v = acc[ms][ns][r] + (VT ? bias[rg] : bvc);
                if (RELU)   v = fmaxf(v, 0.0f);
                if (RES == 1)
                    v += res[(long long)rg * N + cg];
                if (VT) {
                    const long long oaddr =
                        (long long)((cg >> 11) * 4 + (rg >> 8)) * 524288 +
                        (long long)(rg & 255) * 2048 + (cg & 2047);
                    reinterpret_cast<unsigned short*>(out)[oaddr] = f2b(v);
                } else if (OUTBF) {
                    reinterpret_cast<unsigned short*>(out)[(long long)rg * N + cg] = f2b(v);
                } else {
                    reinterpret_cast<float*>(out)[(long long)rg * N + cg] = v;
                }
            }
        }
    }
}

// ---------------- Flash attention: K in LDS (reg-staged dbuf), V direct from global ----------------
// Round-1-proven structure, minus V staging: V fragments load straight from vt[e][t]
// (16B/lane segments, L1-resident tile; VMEM port overlaps the LDS QK reads).
// P fully in-register (swapped QK^T + cvt_pk + permlane32_swap). 1 barrier/iter.
// LDS: 2 * 32*264 * 2B = 33792 B -> reg-limited 2 blocks/CU.
__global__ __launch_bounds__(256, 2) void attn_kernel(
    const unsigned short* __restrict__ QK, const unsigned short* __restrict__ Vt,
    unsigned short* __restrict__ Cat)
{
    __shared__ __align__(16) unsigned short Ks[2][32 * 264];   // [t][d], stride 264 (conflict-free)
    const int tid  = threadIdx.x;
    const int wave = tid >> 6, lane = tid & 63;
    const int l32 = lane & 31, half = lane >> 5;
    const int by = blockIdx.x;              // b*4 + h
    const int h = by & 3, b = by >> 2;
    const int q0 = blockIdx.y * 128;
    const unsigned short* Qb = QK + (long long)b * SS * 2048 + h * 256;
    const unsigned short* Kb = Qb + 1024;
    const unsigned short* vbase = Vt + (long long)by * DD * SS;

    // Q fragments, 32 rows/wave: lane holds Q[q0+w*32+l32][kb*16 + half*8 + j]
    bf16x8 qf[16];
    {
        const unsigned short* qrow = Qb + (long long)(q0 + wave * 32 + l32) * 2048 + half * 8;
#pragma unroll
        for (int kb = 0; kb < 16; ++kb)
            qf[kb] = *reinterpret_cast<const bf16x8*>(qrow + kb * 16);
    }

    f32x16 o[8];
#pragma unroll
    for (int i = 0; i < 8; ++i)
#pragma unroll
        for (int r = 0; r < 16; ++r) o[i][r] = 0.f;
    float lsum = 0.f;   // per-lane partial row-sum for q = l32 (this half's t-subset)

    const int krow = tid >> 3;          // 0..31
    const int kcol = (tid & 7) * 8;     // 0..56 (shorts)

    // direct-global V fragment: B-operand of PV; lane l32 = e row, half picks 16B t-slice
#define VLD(ET, O16) (*reinterpret_cast<const bf16x8*>(                                   \
        &vbase[(long long)((ET) * 32 + l32) * SS + t0 + (O16) + half * 8]))

    uint4 kreg[4];
    // prologue: stage K tile 0 into buffer 0
#pragma unroll
    for (int c = 0; c < 4; ++c)
        kreg[c] = *reinterpret_cast<const uint4*>(&Kb[(long long)krow * 2048 + kcol + c * 64]);
#pragma unroll
    for (int c = 0; c < 4; ++c)
        *reinterpret_cast<uint4*>(&Ks[0][krow * 264 + kcol + c * 64]) = kreg[c];
    __syncthreads();

    for (int t = 0; t < 64; ++t) {
        const int cur = t & 1;
        const int t0 = t * 32;
        // issue next K tile's global loads first; they fly under this whole iteration
        if (t < 63) {
#pragma unroll
            for (int c = 0; c < 4; ++c)
                kreg[c] = *reinterpret_cast<const uint4*>(&Kb[(long long)(t0 + 32 + krow) * 2048 + kcol + c * 64]);
        }

        // swapped QK^T: sc = K_tile . Q^T, split accumulator chains
        f32x16 sc0, sc1;
#pragma unroll
        for (int r = 0; r < 16; ++r) { sc0[r] = 0.f; sc1[r] = 0.f; }
        __builtin_amdgcn_s_setprio(1);
#pragma unroll
        for (int kb = 0; kb < 8; ++kb) {
            bf16x8 kf0 = *reinterpret_cast<const bf16x8*>(&Ks[cur][l32 * 264 + (2 * kb) * 16 + half * 8]);
            bf16x8 kf1 = *reinterpret_cast<const bf16x8*>(&Ks[cur][l32 * 264 + (2 * kb + 1) * 16 + half * 8]);
            sc0 = mfma32(kf0, qf[2 * kb], sc0);
            sc1 = mfma32(kf1, qf[2 * kb + 1], sc1);
        }
        __builtin_amdgcn_s_setprio(0);

        // V fragments for first two e-tiles (L1 latency hides under softmax)
        bf16x8 va0 = VLD(0, 0), va1 = VLD(0, 16);
        bf16x8 vb0 = VLD(1, 0), vb1 = VLD(1, 16);

        // softmax numerator: p = exp2(s); fused pairwise into bf16 packs
        unsigned pk[8];
#pragma unroll
        for (int i = 0; i < 8; ++i) {
            const float pa = exp2f(sc0[2 * i]     + sc1[2 * i]);
            const float pb = exp2f(sc0[2 * i + 1] + sc1[2 * i + 1]);
            lsum += pa + pb;
            pk[i] = cvtpk(pa, pb);
        }
        union { bf16x8 v; unsigned u[4]; } A0, A1;   // A0: t=0..15, A1: t=16..31
        { auto rr = __builtin_amdgcn_permlane32_swap(pk[0], pk[2], false, false); A0.u[0] = rr[0]; A0.u[2] = rr[1]; }
        { auto rr = __builtin_amdgcn_permlane32_swap(pk[1], pk[3], false, false); A0.u[1] = rr[0]; A0.u[3] = rr[1]; }
        { auto rr = __builtin_amdgcn_permlane32_swap(pk[4], pk[6], false, false); A1.u[0] = rr[0]; A1.u[2] = rr[1]; }
        { auto rr = __builtin_amdgcn_permlane32_swap(pk[5], pk[7], false, false); A1.u[1] = rr[0]; A1.u[3] = rr[1]; }

        // PV: rolling 2-et register buffer, reload consumed pair for et+2
        __builtin_amdgcn_s_setprio(1);
        o[0] = mfma32(A0.v, va0, o[0]); o[0] = mfma32(A1.v, va1, o[0]);
        va0 = VLD(2, 0); va1 = VLD(2, 16);
        o[1] = mfma32(A0.v, vb0, o[1]); o[1] = mfma32(A1.v, vb1, o[1]);
        vb0 = VLD(3, 0); vb1 = VLD(3, 16);
        o[2] = mfma32(A0.v, va0, o[2]); o[2] = mfma32(A1.v, va1, o[2]);
        va0 = VLD(4, 0); va1 = VLD(4, 16);
        o[3] = mfma32(A0.v, vb0, o[3]); o[3] = mfma32(A1.v, vb1, o[3]);
        vb0 = VLD(5, 0); vb1 = VLD(5, 16);
        o[4] = mfma32(A0.v, va0, o[4]); o[4] = mfma32(A1.v, va1, o[4]);
        va0 = VLD(6, 0); va1 = VLD(6, 16);
        o[5] = mfma32(A0.v, vb0, o[5]); o[5] = mfma32(A1.v, vb1, o[5]);
        vb0 = VLD(7, 0); vb1 = VLD(7, 16);
        o[6] = mfma32(A0.v, va0, o[6]); o[6] = mfma32(A1.v, va1, o[6]);
        o[7] = mfma32(A0.v, vb0, o[7]); o[7] = mfma32(A1.v, vb1, o[7]);
        __builtin_amdgcn_s_setprio(0);

        // write next K tile into the other buffer, then single barrier.
        // (iter t+1 overwrites Ks[cur]; this barrier fences its readers = this iter's QK)
        if (t < 63) {
            const int nxt = cur ^ 1;
#pragma unroll
            for (int c = 0; c < 4; ++c)
                *reinterpret_cast<uint4*>(&Ks[nxt][krow * 264 + kcol + c * 64]) = kreg[c];
            __syncthreads();
        }
    }
#undef VLD

    // epilogue: full row-sum for q=l32 lives split across the two halves
    lsum += __shfl_xor(lsum, 32);
    const float inv = 1.0f / lsum;
    float invr[16];
#pragma unroll
    for (int r = 0; r < 16; ++r)
        invr[r] = __shfl(inv, (r & 3) + 8 * (r >> 2) + 4 * half);

    const int rowb = b * SS + q0 + wave * 32;
#pragma unroll
    for (int et = 0; et < 8; ++et) {
        const int cg = h * 256 + et * 32 + l32;
#pragma unroll
        for (int r = 0; r < 16; ++r) {
            const int row = (r & 3) + 8 * (r >> 2) + 4 * half;
            Cat[(long long)(rowb + row) * (HH * DD) + cg] = f2b(o[et][r] * invr[r]);
        }
    }
}

// ---------------- launch ----------------
extern "C" void kernel_launch(void* const* d_in, const int* in_sizes, int n_in,
                              void* d_out, int out_size, void* d_ws, size_t ws_size,
                              hipStream_t stream)
{
    const float* x   = (const float*)d_in[0];
    const float* Wq  = (const float*)d_in[1];
    const float* bq  = (const float*)d_in[2];
    const float* Wk  = (const float*)d_in[3];
    const float* bk  = (const float*)d_in[4];
    const float* Wv  = (const float*)d_in[5];
    const float* bv  = (const float*)d_in[6];
    const float* Wo  = (const float*)d_in[7];
    const float* bo  = (const float*)d_in[8];
    const float* g1  = (const float*)d_in[9];
    const float* be1 = (const float*)d_in[10];
    const float* g2  = (const float*)d_in[11];
    const float* be2 = (const float*)d_in[12];
    const float* W1  = (const float*)d_in[13];
    const float* bf1 = (const float*)d_in[14];
    const float* W2  = (const float*)d_in[15];
    const float* bf2 = (const float*)d_in[16];
    float* out = (float*)d_out;

    // ---- workspace layout ----
    char* ws = (char*)d_ws;
    unsigned short* xn1  = (unsigned short*)(ws + 0);           // [16384][256] bf16
    unsigned short* qk   = (unsigned short*)(ws + 8388608);     // [16384][2048] bf16 (Q|K by head)
    unsigned short* cat  = (unsigned short*)(ws + 75497472);    // [16384][1024] bf16
    unsigned short* vt   = (unsigned short*)(ws + 109051904);   // [32][256][2048] bf16
    unsigned short* wqkT = (unsigned short*)(ws + 142606336);   // [2048][256] bf16
    unsigned short* wvT  = (unsigned short*)(ws + 143654912);   // [1024][256] bf16
    unsigned short* woT  = (unsigned short*)(ws + 144179200);   // [256][1024] bf16
    unsigned short* w1T  = (unsigned short*)(ws + 144703488);   // [512][256] bf16
    unsigned short* w2T  = (unsigned short*)(ws + 144965632);   // [256][512] bf16
    float*          qkb  = (float*)(ws + 145227776);            // [2048] f32
    float*          vb   = (float*)(ws + 145235968);            // [1024] f32
    // aliases over dead regions:
    float*          xmid = (float*)(ws + 8388608);              // (qk dead after attn)
    unsigned short* xn2  = (unsigned short*)(ws + 25165824);
    unsigned short* mid  = (unsigned short*)(ws + 33554432);

    // weight transposes (Q scale: 1/16 * log2(e) folded for exp2 softmax)
    transpose_f32_kernel<<<dim3(4, 4, 4),  256, 0, stream>>>(Wq, wqkT,          256,  256, 0, 65536, 4, 65536, QSCALE);
    transpose_f32_kernel<<<dim3(4, 4, 4),  256, 0, stream>>>(Wk, wqkT + 262144, 256,  256, 0, 65536, 4, 65536, 1.0f);
    transpose_f32_kernel<<<dim3(4, 4, 4),  256, 0, stream>>>(Wv, wvT,           256,  256, 0, 65536, 4, 65536, 1.0f);
    transpose_f32_kernel<<<dim3(16, 4, 1), 256, 0, stream>>>(Wo, woT,           256, 1024, 0, 0, 4, 0, 1.0f);
    transpose_f32_kernel<<<dim3(4, 8, 1),  256, 0, stream>>>(W1, w1T,           512,  256, 0, 0, 4, 0, 1.0f);
    transpose_f32_kernel<<<dim3(8, 4, 1),  256, 0, stream>>>(W2, w2T,           256,  512, 0, 0, 4, 0, 1.0f);
    bias_concat_kernel<<<dim3(12), 256, 0, stream>>>(bq, bk, bv, qkb, vb);

    // LN1
    ln_kernel<<<dim3(4096), 256, 0, stream>>>(x, g1, be1, xn1);

    // fused Q|K projection (2048 blocks)
    gemm_kernel<false, 0, true, 4, false><<<dim3(128, 16), 256, 0, stream>>>(
        xn1, wqkT, qkb, nullptr, qk, MM, 2048, 256);
    // V^T projection straight into vt layout (1024 blocks)
    gemm_kernel<false, 0, true, 4, true><<<dim3(8, 128), 256, 0, stream>>>(
        wvT, xn1, vb, nullptr, vt, 1024, MM, 256);

    // flash attention (32x32 MFMA, 128 q-rows/block, 512 blocks = 2/CU)
    attn_kernel<<<dim3(32, 16), 256, 0, stream>>>(qk, vt, cat);

    // Wo projection + residual(x) -> xmid (f32); 128x64 tiles -> 512 blocks
    gemm_kernel<false, 1, false, 2, false><<<dim3(128, 4), 256, 0, stream>>>(
        cat, woT, bo, x, xmid, MM, 256, 1024);

    // LN2
    ln_kernel<<<dim3(4096), 256, 0, stream>>>(xmid, g2, be2, xn2);

    // FFN1 + ReLU; 128x64 tiles -> 1024 blocks
    gemm_kernel<true, 0, true, 2, false><<<dim3(128, 8), 256, 0, stream>>>(
        xn2, w1T, bf1, nullptr, mid, MM, 512, 256);

    // FFN2 + residual(xmid) -> d_out (f32); 128x64 tiles -> 512 blocks
    gemm_kernel<false, 1, false, 2, false><<<dim3(128, 4), 256, 0, stream>>>(
        mid, w2T, bf2, xmid, out, MM, 256, 512);

    (void)in_sizes; (void)n_in; (void)out_size; (void)ws_size;
}

// Round 5
// 389.200 us; speedup vs baseline: 2.4076x; 1.2974x over previous
//
#include <hip/hip_runtime.h>

typedef __bf16 bf16x8 __attribute__((ext_vector_type(8)));
typedef float  f32x4  __attribute__((ext_vector_type(4)));
typedef float  f32x16 __attribute__((ext_vector_type(16)));

__device__ __forceinline__ unsigned short f2b(float f) {
    union { float f; unsigned int v; } c; c.f = f;
    unsigned int u = c.v;
    unsigned int r = u + 0x7FFFu + ((u >> 16) & 1u);   // RNE
    return (unsigned short)(r >> 16);
}
__device__ __forceinline__ f32x4 mfma16(bf16x8 a, bf16x8 b, f32x4 c) {
    return __builtin_amdgcn_mfma_f32_16x16x32_bf16(a, b, c, 0, 0, 0);
}
__device__ __forceinline__ f32x16 mfma32(bf16x8 a, bf16x8 b, f32x16 c) {
    return __builtin_amdgcn_mfma_f32_32x32x16_bf16(a, b, c, 0, 0, 0);
}
// pack two f32 -> 2xbf16 in one u32 (lo = a, hi = b), RNE
__device__ __forceinline__ unsigned cvtpk(float a, float b) {
    unsigned r;
    asm("v_cvt_pk_bf16_f32 %0, %1, %2" : "=v"(r) : "v"(a), "v"(b));
    return r;
}

// ---------------- constants ----------------
#define BB 8
#define SS 2048
#define DD 256
#define HH 4
#define FF 512
#define MM (BB * SS)   // 16384
// log2(e) folded into Q scale so softmax uses exp2 directly
#define QSCALE (0.0625f * 1.44269504088896340736f)

// ---------------- transpose f32 -> bf16 with scale ----------------
__global__ __launch_bounds__(256) void transpose_f32_kernel(
    const float* __restrict__ in, unsigned short* __restrict__ out,
    int inS, int outS, long long inZa, long long inZb, int zmod, long long outZ,
    float scale)
{
    __shared__ unsigned short T[64][72];
    const int z = blockIdx.z;
    in  += (long long)(z / zmod) * inZa + (long long)(z % zmod) * inZb;
    out += (long long)z * outZ;
    const int r0 = blockIdx.x * 64, c0 = blockIdx.y * 64;
    const int tid = threadIdx.x;
    const int row = tid >> 3;           // 0..31
    const int col = (tid & 7) * 8;      // 0..56
#pragma unroll
    for (int c = 0; c < 2; ++c) {
        int rr = c * 32 + row;
        const float4 a = *reinterpret_cast<const float4*>(&in[(long long)(r0 + rr) * inS + c0 + col]);
        const float4 b = *reinterpret_cast<const float4*>(&in[(long long)(r0 + rr) * inS + c0 + col + 4]);
        alignas(16) unsigned short t[8] = {
            f2b(a.x * scale), f2b(a.y * scale), f2b(a.z * scale), f2b(a.w * scale),
            f2b(b.x * scale), f2b(b.y * scale), f2b(b.z * scale), f2b(b.w * scale) };
        *reinterpret_cast<uint4*>(&T[rr][col]) = *reinterpret_cast<const uint4*>(t);
    }
    __syncthreads();
#pragma unroll
    for (int c = 0; c < 2; ++c) {
        int orow = c * 32 + row;
        alignas(16) unsigned short tmp[8];
#pragma unroll
        for (int j = 0; j < 8; ++j) tmp[j] = T[col + j][orow];
        *reinterpret_cast<uint4*>(&out[(long long)(c0 + orow) * outS + r0 + col]) =
            *reinterpret_cast<const uint4*>(tmp);
    }
}

// ---------------- bias concat: qkb[2048] = {bq*QSCALE, bk}, vb[1024] = bv ----------------
__global__ __launch_bounds__(256) void bias_concat_kernel(
    const float* __restrict__ bq, const float* __restrict__ bk,
    const float* __restrict__ bv, float* __restrict__ qkb, float* __restrict__ vb)
{
    const int i = blockIdx.x * 256 + threadIdx.x;
    if (i < 1024)       qkb[i] = bq[i] * QSCALE;
    else if (i < 2048)  qkb[i] = bk[i - 1024];
    else                vb[i - 2048] = bv[i - 2048];
}

// ---------------- LayerNorm: one wave per 256-elem row, f32 in -> bf16 out ----------------
__global__ __launch_bounds__(256) void ln_kernel(
    const float* __restrict__ in, const float* __restrict__ g,
    const float* __restrict__ bta, unsigned short* __restrict__ out)
{
    const int tid  = threadIdx.x;
    const int wave = tid >> 6, lane = tid & 63;
    const int row  = blockIdx.x * 4 + wave;
    const float4 v = reinterpret_cast<const float4*>(in)[(long long)row * 64 + lane];
    float x[4] = { v.x, v.y, v.z, v.w };
    float s = x[0] + x[1] + x[2] + x[3];
    float q = x[0]*x[0] + x[1]*x[1] + x[2]*x[2] + x[3]*x[3];
#pragma unroll
    for (int off = 1; off < 64; off <<= 1) {
        s += __shfl_xor(s, off);
        q += __shfl_xor(q, off);
    }
    const float mean = s * (1.0f / 256.0f);
    const float var  = q * (1.0f / 256.0f) - mean * mean;
    const float rs   = rsqrtf(var + 1e-5f);
    const float4 gv = reinterpret_cast<const float4*>(g)[lane];
    const float4 bv = reinterpret_cast<const float4*>(bta)[lane];
    unsigned short y[4];
    y[0] = f2b((x[0] - mean) * rs * gv.x + bv.x);
    y[1] = f2b((x[1] - mean) * rs * gv.y + bv.y);
    y[2] = f2b((x[2] - mean) * rs * gv.z + bv.z);
    y[3] = f2b((x[3] - mean) * rs * gv.w + bv.w);
    uint2 o;
    o.x = (unsigned int)y[0] | ((unsigned int)y[1] << 16);
    o.y = (unsigned int)y[2] | ((unsigned int)y[3] << 16);
    reinterpret_cast<uint2*>(out)[(long long)row * 64 + lane] = o;
}

// ---------------- GEMM: C[MxN] = A[MxK] @ B  (B given as BT[N x K], bf16) ----------------
// Operand-swapped MFMA: D = mfma(bf, af) puts col=l16 on the M side and row=quad*4+r on
// the N side, so each thread owns 4 CONSECUTIVE n of one m-row -> vectorized epilogue
// (float4 bias/residual loads, uint2/float4 C stores; 4x fewer store instructions).
template <bool RELU, int RES, bool OUTBF, int NS, bool VT>
__global__ __launch_bounds__(256) void gemm_kernel(
    const unsigned short* __restrict__ A, const unsigned short* __restrict__ BT,
    const float* __restrict__ bias, const float* __restrict__ res,
    void* __restrict__ out, int M, int N, int K)
{
    __shared__ unsigned short As[128 * 40];
    __shared__ unsigned short Bs[(NS == 4 ? 128 : 64) * 40];
    const int tid  = threadIdx.x;
    const int wave = tid >> 6, lane = tid & 63;
    const int quad = lane >> 4, l16 = lane & 15;
    const int wm = wave >> 1, wn = wave & 1;
    const int WN = NS * 16;                        // wave n-width
    const int m0 = blockIdx.x * 128, n0 = blockIdx.y * (2 * WN);

    f32x4 acc[4][NS];
#pragma unroll
    for (int i = 0; i < 4; ++i)
#pragma unroll
        for (int j = 0; j < NS; ++j) acc[i][j] = (f32x4){0.f, 0.f, 0.f, 0.f};

    const int srow = tid >> 2;          // 0..63
    const int scol = (tid & 3) * 8;     // 0,8,16,24

    for (int k0 = 0; k0 < K; k0 += 32) {
        __syncthreads();
#pragma unroll
        for (int c = 0; c < 2; ++c) {
            const int r = c * 64 + srow;
            *reinterpret_cast<uint4*>(&As[r * 40 + scol]) =
                *reinterpret_cast<const uint4*>(&A[(long long)(m0 + r) * K + k0 + scol]);
        }
        {
            *reinterpret_cast<uint4*>(&Bs[srow * 40 + scol]) =
                *reinterpret_cast<const uint4*>(&BT[(long long)(n0 + srow) * K + k0 + scol]);
            if (NS == 4) {
                const int r = 64 + srow;
                *reinterpret_cast<uint4*>(&Bs[r * 40 + scol]) =
                    *reinterpret_cast<const uint4*>(&BT[(long long)(n0 + r) * K + k0 + scol]);
            }
        }
        __syncthreads();
        bf16x8 af[4], bf[NS];
#pragma unroll
        for (int ms = 0; ms < 4; ++ms)
            af[ms] = *reinterpret_cast<const bf16x8*>(&As[(wm * 64 + ms * 16 + l16) * 40 + quad * 8]);
#pragma unroll
        for (int ns = 0; ns < NS; ++ns)
            bf[ns] = *reinterpret_cast<const bf16x8*>(&Bs[(wn * WN + ns * 16 + l16) * 40 + quad * 8]);
#pragma unroll
        for (int ms = 0; ms < 4; ++ms)
#pragma unroll
            for (int ns = 0; ns < NS; ++ns)
                acc[ms][ns] = mfma16(bf[ns], af[ms], acc[ms][ns]);   // swapped operands
    }

    // epilogue: thread owns C[m][nb..nb+3], m = ...+l16, nb = ...+quad*4
#pragma unroll
    for (int ms = 0; ms < 4; ++ms) {
        const int m = m0 + wm * 64 + ms * 16 + l16;
#pragma unroll
        for (int ns = 0; ns < NS; ++ns) {
            const int nb = n0 + wn * WN + ns * 16 + quad * 4;
            float v0 = acc[ms][ns][0], v1 = acc[ms][ns][1];
            float v2 = acc[ms][ns][2], v3 = acc[ms][ns][3];
            if (VT) {
                const float bm = bias[m];
                v0 += bm; v1 += bm; v2 += bm; v3 += bm;
            } else {
                const float4 b4 = *reinterpret_cast<const float4*>(&bias[nb]);
                v0 += b4.x; v1 += b4.y; v2 += b4.z; v3 += b4.w;
            }
            if (RELU) {
                v0 = fmaxf(v0, 0.f); v1 = fmaxf(v1, 0.f);
                v2 = fmaxf(v2, 0.f); v3 = fmaxf(v3, 0.f);
            }
            if (RES == 1) {
                const float4 r4 = *reinterpret_cast<const float4*>(&res[(long long)m * N + nb]);
                v0 += r4.x; v1 += r4.y; v2 += r4.z; v3 += r4.w;
            }
            if (VT) {
                // m = e (M=1024), nb = t-group (N=16384) -> vt[(b*4+h)][e][t], 4 consecutive t
                const long long oaddr =
                    (long long)((nb >> 11) * 4 + (m >> 8)) * 524288 +
                    (long long)(m & 255) * 2048 + (nb & 2047);
                uint2 o;
                o.x = (unsigned int)f2b(v0) | ((unsigned int)f2b(v1) << 16);
                o.y = (unsigned int)f2b(v2) | ((unsigned int)f2b(v3) << 16);
                *reinterpret_cast<uint2*>(&reinterpret_cast<unsigned short*>(out)[oaddr]) = o;
            } else if (OUTBF) {
                uint2 o;
                o.x = (unsigned int)f2b(v0) | ((unsigned int)f2b(v1) << 16);
                o.y = (unsigned int)f2b(v2) | ((unsigned int)f2b(v3) << 16);
                *reinterpret_cast<uint2*>(
                    &reinterpret_cast<unsigned short*>(out)[(long long)m * N + nb]) = o;
            } else {
                float4 o4; o4.x = v0; o4.y = v1; o4.z = v2; o4.w = v3;
                *reinterpret_cast<float4*>(
                    &reinterpret_cast<float*>(out)[(long long)m * N + nb]) = o4;
            }
        }
    }
}

// ---------------- Flash attention (round-1 proven structure, exp2 softmax) ----------------
// K and V double-buffered in LDS via reg staging; in-register P (swapped QK^T + cvt_pk +
// permlane32_swap); 1 barrier/iter. LDS: 2*(32*264 + 256*40)*2B = 74752 B -> 2 blocks/CU.
__global__ __launch_bounds__(256, 2) void attn_kernel(
    const unsigned short* __restrict__ QK, const unsigned short* __restrict__ Vt,
    unsigned short* __restrict__ Cat)
{
    __shared__ __align__(16) unsigned short Ks[2][32 * 264];   // [t][d], stride 264
    __shared__ __align__(16) unsigned short Vs[2][256 * 40];   // [e][t], stride 40
    const int tid  = threadIdx.x;
    const int wave = tid >> 6, lane = tid & 63;
    const int l32 = lane & 31, half = lane >> 5;
    const int by = blockIdx.x;              // b*4 + h
    const int h = by & 3, b = by >> 2;
    const int q0 = blockIdx.y * 128;
    const unsigned short* Qb = QK + (long long)b * SS * 2048 + h * 256;
    const unsigned short* Kb = Qb + 1024;
    const unsigned short* vbase = Vt + (long long)by * DD * SS;

    // Q fragments, 32 rows/wave: lane holds Q[q0+w*32+l32][kb*16 + half*8 + j]
    bf16x8 qf[16];
    {
        const unsigned short* qrow = Qb + (long long)(q0 + wave * 32 + l32) * 2048 + half * 8;
#pragma unroll
        for (int kb = 0; kb < 16; ++kb)
            qf[kb] = *reinterpret_cast<const bf16x8*>(qrow + kb * 16);
    }

    f32x16 o[8];
#pragma unroll
    for (int i = 0; i < 8; ++i)
#pragma unroll
        for (int r = 0; r < 16; ++r) o[i][r] = 0.f;
    float lsum = 0.f;   // per-lane partial row-sum for q = l32 (this half's t-subset)

    const int krow = tid >> 3;          // 0..31
    const int kcol = (tid & 7) * 8;     // 0..56 (shorts)
    const int ve   = tid >> 2;          // 0..63 (base V row)
    const int vtf  = (tid & 3) * 8;     // 0..24 (t offset, shorts)

    uint4 kreg[4], vreg[4];
    // prologue: stage tile 0 into buffer 0
#pragma unroll
    for (int c = 0; c < 4; ++c)
        kreg[c] = *reinterpret_cast<const uint4*>(&Kb[(long long)krow * 2048 + kcol + c * 64]);
#pragma unroll
    for (int c = 0; c < 4; ++c)
        vreg[c] = *reinterpret_cast<const uint4*>(&vbase[(long long)(ve + c * 64) * SS + vtf]);
#pragma unroll
    for (int c = 0; c < 4; ++c)
        *reinterpret_cast<uint4*>(&Ks[0][krow * 264 + kcol + c * 64]) = kreg[c];
#pragma unroll
    for (int c = 0; c < 4; ++c)
        *reinterpret_cast<uint4*>(&Vs[0][(ve + c * 64) * 40 + vtf]) = vreg[c];
    __syncthreads();

    for (int t = 0; t < 64; ++t) {
        const int cur = t & 1;
        // issue next-tile global loads early (latency hides under compute)
        if (t < 63) {
            const int t1 = (t + 1) * 32;
#pragma unroll
            for (int c = 0; c < 4; ++c)
                kreg[c] = *reinterpret_cast<const uint4*>(&Kb[(long long)(t1 + krow) * 2048 + kcol + c * 64]);
#pragma unroll
            for (int c = 0; c < 4; ++c)
                vreg[c] = *reinterpret_cast<const uint4*>(&vbase[(long long)(ve + c * 64) * SS + t1 + vtf]);
        }

        // swapped QK^T: sc = K_tile . Q^T -> lane holds S[q=l32][t-subset], split acc chain
        f32x16 sc0, sc1;
#pragma unroll
        for (int r = 0; r < 16; ++r) { sc0[r] = 0.f; sc1[r] = 0.f; }
        __builtin_amdgcn_s_setprio(1);
#pragma unroll
        for (int kb = 0; kb < 8; ++kb) {
            bf16x8 kf0 = *reinterpret_cast<const bf16x8*>(&Ks[cur][l32 * 264 + (2 * kb) * 16 + half * 8]);
            bf16x8 kf1 = *reinterpret_cast<const bf16x8*>(&Ks[cur][l32 * 264 + (2 * kb + 1) * 16 + half * 8]);
            sc0 = mfma32(kf0, qf[2 * kb], sc0);
            sc1 = mfma32(kf1, qf[2 * kb + 1], sc1);
        }
        __builtin_amdgcn_s_setprio(0);

        // softmax numerator: p = exp2(s) (log2e folded into Q scale)
        float p[16];
#pragma unroll
        for (int r = 0; r < 16; ++r) {
            p[r] = exp2f(sc0[r] + sc1[r]);
            lsum += p[r];
        }

        // pack P -> PV A-fragments fully in-register (cvt_pk + permlane32_swap)
        unsigned pk[8];
#pragma unroll
        for (int i = 0; i < 8; ++i) pk[i] = cvtpk(p[2 * i], p[2 * i + 1]);
        union { bf16x8 v; unsigned u[4]; } A0, A1;   // A0: t=0..15, A1: t=16..31
        { auto rr = __builtin_amdgcn_permlane32_swap(pk[0], pk[2], false, false); A0.u[0] = rr[0]; A0.u[2] = rr[1]; }
        { auto rr = __builtin_amdgcn_permlane32_swap(pk[1], pk[3], false, false); A0.u[1] = rr[0]; A0.u[3] = rr[1]; }
        { auto rr = __builtin_amdgcn_permlane32_swap(pk[4], pk[6], false, false); A1.u[0] = rr[0]; A1.u[2] = rr[1]; }
        { auto rr = __builtin_amdgcn_permlane32_swap(pk[5], pk[7], false, false); A1.u[1] = rr[0]; A1.u[3] = rr[1]; }

        // PV: B = V^T tile from Vs; 8 e-tiles x 2 k-steps
        __builtin_amdgcn_s_setprio(1);
#pragma unroll
        for (int et = 0; et < 8; ++et) {
            bf16x8 vf0 = *reinterpret_cast<const bf16x8*>(&Vs[cur][(et * 32 + l32) * 40 + half * 8]);
            bf16x8 vf1 = *reinterpret_cast<const bf16x8*>(&Vs[cur][(et * 32 + l32) * 40 + 16 + half * 8]);
            o[et] = mfma32(A0.v, vf0, o[et]);
            o[et] = mfma32(A1.v, vf1, o[et]);
        }
        __builtin_amdgcn_s_setprio(0);

        // write next tile into the other buffer, then single barrier
        if (t < 63) {
            const int nxt = cur ^ 1;
#pragma unroll
            for (int c = 0; c < 4; ++c)
                *reinterpret_cast<uint4*>(&Ks[nxt][krow * 264 + kcol + c * 64]) = kreg[c];
#pragma unroll
            for (int c = 0; c < 4; ++c)
                *reinterpret_cast<uint4*>(&Vs[nxt][(ve + c * 64) * 40 + vtf]) = vreg[c];
            __syncthreads();
        }
    }

    // epilogue: full row-sum for q=l32 lives split across the two halves
    lsum += __shfl_xor(lsum, 32);
    const float inv = 1.0f / lsum;
    float invr[16];
#pragma unroll
    for (int r = 0; r < 16; ++r)
        invr[r] = __shfl(inv, (r & 3) + 8 * (r >> 2) + 4 * half);

    const int rowb = b * SS + q0 + wave * 32;
#pragma unroll
    for (int et = 0; et < 8; ++et) {
        const int cg = h * 256 + et * 32 + l32;
#pragma unroll
        for (int r = 0; r < 16; ++r) {
            const int row = (r & 3) + 8 * (r >> 2) + 4 * half;
            Cat[(long long)(rowb + row) * (HH * DD) + cg] = f2b(o[et][r] * invr[r]);
        }
    }
}

// ---------------- launch ----------------
extern "C" void kernel_launch(void* const* d_in, const int* in_sizes, int n_in,
                              void* d_out, int out_size, void* d_ws, size_t ws_size,
                              hipStream_t stream)
{
    const float* x   = (const float*)d_in[0];
    const float* Wq  = (const float*)d_in[1];
    const float* bq  = (const float*)d_in[2];
    const float* Wk  = (const float*)d_in[3];
    const float* bk  = (const float*)d_in[4];
    const float* Wv  = (const float*)d_in[5];
    const float* bv  = (const float*)d_in[6];
    const float* Wo  = (const float*)d_in[7];
    const float* bo  = (const float*)d_in[8];
    const float* g1  = (const float*)d_in[9];
    const float* be1 = (const float*)d_in[10];
    const float* g2  = (const float*)d_in[11];
    const float* be2 = (const float*)d_in[12];
    const float* W1  = (const float*)d_in[13];
    const float* bf1 = (const float*)d_in[14];
    const float* W2  = (const float*)d_in[15];
    const float* bf2 = (const float*)d_in[16];
    float* out = (float*)d_out;

    // ---- workspace layout ----
    char* ws = (char*)d_ws;
    unsigned short* xn1  = (unsigned short*)(ws + 0);           // [16384][256] bf16
    unsigned short* qk   = (unsigned short*)(ws + 8388608);     // [16384][2048] bf16 (Q|K by head)
    unsigned short* cat  = (unsigned short*)(ws + 75497472);    // [16384][1024] bf16
    unsigned short* vt   = (unsigned short*)(ws + 109051904);   // [32][256][2048] bf16
    unsigned short* wqkT = (unsigned short*)(ws + 142606336);   // [2048][256] bf16
    unsigned short* wvT  = (unsigned short*)(ws + 143654912);   // [1024][256] bf16
    unsigned short* woT  = (unsigned short*)(ws + 144179200);   // [256][1024] bf16
    unsigned short* w1T  = (unsigned short*)(ws + 144703488);   // [512][256] bf16
    unsigned short* w2T  = (unsigned short*)(ws + 144965632);   // [256][512] bf16
    float*          qkb  = (float*)(ws + 145227776);            // [2048] f32
    float*          vb   = (float*)(ws + 145235968);            // [1024] f32
    // aliases over dead regions:
    float*          xmid = (float*)(ws + 8388608);              // (qk dead after attn)
    unsigned short* xn2  = (unsigned short*)(ws + 25165824);
    unsigned short* mid  = (unsigned short*)(ws + 33554432);

    // weight transposes (Q scale: 1/16 * log2(e) folded for exp2 softmax)
    transpose_f32_kernel<<<dim3(4, 4, 4),  256, 0, stream>>>(Wq, wqkT,          256,  256, 0, 65536, 4, 65536, QSCALE);
    transpose_f32_kernel<<<dim3(4, 4, 4),  256, 0, stream>>>(Wk, wqkT + 262144, 256,  256, 0, 65536, 4, 65536, 1.0f);
    transpose_f32_kernel<<<dim3(4, 4, 4),  256, 0, stream>>>(Wv, wvT,           256,  256, 0, 65536, 4, 65536, 1.0f);
    transpose_f32_kernel<<<dim3(16, 4, 1), 256, 0, stream>>>(Wo, woT,           256, 1024, 0, 0, 4, 0, 1.0f);
    transpose_f32_kernel<<<dim3(4, 8, 1),  256, 0, stream>>>(W1, w1T,           512,  256, 0, 0, 4, 0, 1.0f);
    transpose_f32_kernel<<<dim3(8, 4, 1),  256, 0, stream>>>(W2, w2T,           256,  512, 0, 0, 4, 0, 1.0f);
    bias_concat_kernel<<<dim3(12), 256, 0, stream>>>(bq, bk, bv, qkb, vb);

    // LN1
    ln_kernel<<<dim3(4096), 256, 0, stream>>>(x, g1, be1, xn1);

    // fused Q|K projection (2048 blocks)
    gemm_kernel<false, 0, true, 4, false><<<dim3(128, 16), 256, 0, stream>>>(
        xn1, wqkT, qkb, nullptr, qk, MM, 2048, 256);
    // V^T projection straight into vt layout (1024 blocks)
    gemm_kernel<false, 0, true, 4, true><<<dim3(8, 128), 256, 0, stream>>>(
        wvT, xn1, vb, nullptr, vt, 1024, MM, 256);

    // flash attention (32x32 MFMA, 128 q-rows/block, 512 blocks = 2/CU)
    attn_kernel<<<dim3(32, 16), 256, 0, stream>>>(qk, vt, cat);

    // Wo projection + residual(x) -> xmid (f32); 128x64 tiles -> 512 blocks
    gemm_kernel<false, 1, false, 2, false><<<dim3(128, 4), 256, 0, stream>>>(
        cat, woT, bo, x, xmid, MM, 256, 1024);

    // LN2
    ln_kernel<<<dim3(4096), 256, 0, stream>>>(xmid, g2, be2, xn2);

    // FFN1 + ReLU; 128x64 tiles -> 1024 blocks
    gemm_kernel<true, 0, true, 2, false><<<dim3(128, 8), 256, 0, stream>>>(
        xn2, w1T, bf1, nullptr, mid, MM, 512, 256);

    // FFN2 + residual(xmid) -> d_out (f32); 128x64 tiles -> 512 blocks
    gemm_kernel<false, 1, false, 2, false><<<dim3(128, 4), 256, 0, stream>>>(
        mid, w2T, bf2, xmid, out, MM, 256, 512);

    (void)in_sizes; (void)n_in; (void)out_size; (void)ws_size;
}